// Round 5
// baseline (863.836 us; speedup 1.0000x reference)
//
#include <hip/hip_runtime.h>

#define CCH 256      // channels
#define KTOT 512     // mean(256) ++ x_dst(256)
#define GM_BM 128    // rows per block in GEMM
#define GM_BK 64     // K-step
#define GM_TH 512    // threads (8 waves)
#define LDST 72      // padded LDS stride (bf16 elems): 36 words -> balanced banks
#define SCB 2048     // scan elems per block (256 thr x 8)

using f32x4  = __attribute__((ext_vector_type(4))) float;
using bf16x8 = __attribute__((ext_vector_type(8))) short;
using s16x4  = __attribute__((ext_vector_type(4))) short;

__device__ __forceinline__ unsigned short f2bf(float f) {
    union { float f; unsigned u; } v; v.f = f;
    unsigned r = v.u + 0x7FFFu + ((v.u >> 16) & 1u);   // RNE
    return (unsigned short)(r >> 16);
}
__device__ __forceinline__ float bf2f(short h) {
    union { unsigned u; float f; } v;
    v.u = ((unsigned)(unsigned short)h) << 16;
    return v.f;
}

// ---------------- fp32 -> bf16 convert ----------------
__global__ __launch_bounds__(256)
void cvt_bf16(const float* __restrict__ x, unsigned short* __restrict__ y, long n) {
    long i = ((long)blockIdx.x * 256 + threadIdx.x) * 8;
    if (i >= n) return;
    float4 a = *(const float4*)(x + i);
    float4 b = *(const float4*)(x + i + 4);
    bf16x8 pk;
    pk[0]=(short)f2bf(a.x); pk[1]=(short)f2bf(a.y); pk[2]=(short)f2bf(a.z); pk[3]=(short)f2bf(a.w);
    pk[4]=(short)f2bf(b.x); pk[5]=(short)f2bf(b.y); pk[6]=(short)f2bf(b.z); pk[7]=(short)f2bf(b.w);
    *(bf16x8*)(y + i) = pk;
}

// ------- W concat + bf16: out[l][col][k] = (k<256 ? Wl[l][col][k] : Wr[l][col][k-256]) -------
__global__ __launch_bounds__(256)
void cvt_wcat(const float* __restrict__ Wl, const float* __restrict__ Wr,
              unsigned short* __restrict__ out) {
    const int l = blockIdx.y;
    const float* wl = Wl + (size_t)l * CCH * CCH;
    const float* wr = Wr + (size_t)l * CCH * CCH;
    unsigned short* o = out + (size_t)l * CCH * KTOT;
    int idx = (blockIdx.x * 256 + threadIdx.x) * 8;     // 0..65528
    int col = idx >> 8, k = idx & 255;
    {
        float4 a = *(const float4*)(wl + col * CCH + k);
        float4 b = *(const float4*)(wl + col * CCH + k + 4);
        bf16x8 pk;
        pk[0]=(short)f2bf(a.x); pk[1]=(short)f2bf(a.y); pk[2]=(short)f2bf(a.z); pk[3]=(short)f2bf(a.w);
        pk[4]=(short)f2bf(b.x); pk[5]=(short)f2bf(b.y); pk[6]=(short)f2bf(b.z); pk[7]=(short)f2bf(b.w);
        *(bf16x8*)(o + (size_t)col * KTOT + k) = pk;
    }
    {
        float4 a = *(const float4*)(wr + col * CCH + k);
        float4 b = *(const float4*)(wr + col * CCH + k + 4);
        bf16x8 pk;
        pk[0]=(short)f2bf(a.x); pk[1]=(short)f2bf(a.y); pk[2]=(short)f2bf(a.z); pk[3]=(short)f2bf(a.w);
        pk[4]=(short)f2bf(b.x); pk[5]=(short)f2bf(b.y); pk[6]=(short)f2bf(b.z); pk[7]=(short)f2bf(b.w);
        *(bf16x8*)(o + (size_t)col * KTOT + CCH + k) = pk;
    }
}

// ---------------- CSR build ----------------
__global__ __launch_bounds__(256)
void hist_kernel(const int* __restrict__ ei, int E, int* __restrict__ cnt) {
    int e = blockIdx.x * blockDim.x + threadIdx.x;
    if (e < E) atomicAdd(&cnt[ei[E + e]], 1);
}

__global__ __launch_bounds__(256)
void scan_part(const int* __restrict__ cnt, int N, int* __restrict__ bsum) {
    __shared__ int sw[4];
    int t = threadIdx.x;
    int base = blockIdx.x * SCB + t * 8;
    int s = 0;
#pragma unroll
    for (int j = 0; j < 8; ++j) { int idx = base + j; s += (idx < N) ? cnt[idx] : 0; }
    for (int m = 1; m < 64; m <<= 1) s += __shfl_xor(s, m);
    if ((t & 63) == 0) sw[t >> 6] = s;
    __syncthreads();
    if (t == 0) bsum[blockIdx.x] = sw[0] + sw[1] + sw[2] + sw[3];
}

__global__ __launch_bounds__(256)
void scan_bsum(int* __restrict__ ba, int* __restrict__ bb, int nb) {
    int* b = blockIdx.x ? bb : ba;
    __shared__ int s[256];
    int t = threadIdx.x;
    int v = (t < nb) ? b[t] : 0;
    s[t] = v;
    __syncthreads();
    for (int o = 1; o < 256; o <<= 1) {
        int u = 0;
        if (t >= o) u = s[t - o];
        __syncthreads();
        if (t >= o) s[t] += u;
        __syncthreads();
    }
    if (t < nb) b[t] = s[t] - v;   // exclusive
}

__global__ __launch_bounds__(256)
void scan_apply(const int* __restrict__ cnt, const int* __restrict__ bsum,
                int N, int E, int* __restrict__ rowstart, int* __restrict__ cursor) {
    __shared__ int sw[4];
    int t = threadIdx.x;
    int base = blockIdx.x * SCB + t * 8;
    int v[8]; int s = 0;
#pragma unroll
    for (int j = 0; j < 8; ++j) { int idx = base + j; v[j] = (idx < N) ? cnt[idx] : 0; s += v[j]; }
    int own = s;
    for (int m = 1; m < 64; m <<= 1) {
        int u = __shfl_up(s, m);
        if ((t & 63) >= m) s += u;
    }
    if ((t & 63) == 63) sw[t >> 6] = s;
    __syncthreads();
    int w = t >> 6, woff = 0;
    if (w > 0) woff += sw[0];
    if (w > 1) woff += sw[1];
    if (w > 2) woff += sw[2];
    int excl = bsum[blockIdx.x] + woff + s - own;
#pragma unroll
    for (int j = 0; j < 8; ++j) {
        int idx = base + j;
        if (idx < N) { rowstart[idx] = excl; excl += v[j]; cursor[idx] = 0; }
    }
    if (blockIdx.x == 0 && t == 0) rowstart[N] = E;
}

__global__ __launch_bounds__(256)
void fill_kernel(const int* __restrict__ ei, int E, const int* __restrict__ rowstart,
                 int* __restrict__ cursor, int* __restrict__ elist) {
    int e = blockIdx.x * blockDim.x + threadIdx.x;
    if (e < E) {
        int dst = ei[E + e];
        int p = atomicAdd(&cursor[dst], 1);
        elist[rowstart[dst] + p] = ei[e];
    }
}

// ------------- gather + mean (bf16): one HALF-wave (32 lanes x 16B) per node -------------
__global__ __launch_bounds__(256)
void gather_mean(const unsigned short* __restrict__ xsrc, const int* __restrict__ rowstart,
                 const int* __restrict__ elist, unsigned short* __restrict__ mean, int N) {
    int node = (blockIdx.x * blockDim.x + threadIdx.x) >> 5;
    int ln   = threadIdx.x & 31;
    if (node >= N) return;
    int lo = rowstart[node], hi = rowstart[node + 1];
    float a[8] = {0.f,0.f,0.f,0.f,0.f,0.f,0.f,0.f};
    for (int i = lo; i < hi; ++i) {
        int s = elist[i];
        bf16x8 v = *((const bf16x8*)(xsrc + (size_t)s * CCH) + ln);
#pragma unroll
        for (int j = 0; j < 8; ++j) a[j] += bf2f(v[j]);
    }
    float r = (hi > lo) ? 1.0f / (float)(hi - lo) : 0.0f;
    bf16x8 pk;
#pragma unroll
    for (int j = 0; j < 8; ++j) pk[j] = (short)f2bf(a[j] * r);
    *((bf16x8*)(mean + (size_t)node * CCH) + ln) = pk;
}

// ------- fused: h = LNReLU( [mean|xdst] @ Bcat^T + bl ); write fp32 or bf16 -------
__global__ __launch_bounds__(GM_TH, 3)
void sage_gemm_ln(const unsigned short* __restrict__ mean,
                  const unsigned short* __restrict__ xdst,
                  const unsigned short* __restrict__ Bcat,   // [256][512] bf16
                  const float* __restrict__ bl,
                  const float* __restrict__ gamma, const float* __restrict__ beta,
                  float* __restrict__ outf, unsigned short* __restrict__ outb, int Nrows)
{
    __shared__ __align__(16) unsigned short As[GM_BM][LDST];
    __shared__ __align__(16) unsigned short Bs[CCH][LDST];

    const int tid  = threadIdx.x;
    const int lane = tid & 63;
    const int w    = tid >> 6;                 // 0..7, wave w owns rows w*16..w*16+15
    const long brow = (long)blockIdx.x * GM_BM;

    f32x4 acc[16];
#pragma unroll
    for (int f = 0; f < 16; ++f) acc[f] = (f32x4){0.f, 0.f, 0.f, 0.f};

    for (int kb = 0; kb < KTOT; kb += GM_BK) {
        const unsigned short* asrc = (kb < CCH) ? mean : xdst;
        const int akk = kb & (CCH - 1);
        // ---- stage A: 128 rows x 64 k; chunk c -> row=c>>3, k8=c&7 ----
#pragma unroll
        for (int i = 0; i < 2; ++i) {
            int c = tid + i * GM_TH;
            int row = c >> 3, k8 = c & 7;
            long grow = brow + row;
            bf16x8 pk;
            if (grow < Nrows) {
                pk = *(const bf16x8*)(asrc + grow * CCH + akk + k8 * 8);
            } else {
#pragma unroll
                for (int j = 0; j < 8; ++j) pk[j] = 0;
            }
            *(bf16x8*)&As[row][k8 * 8] = pk;
        }
        // ---- stage B: 256 cols x 64 k from Bcat (bf16, no cvt) ----
#pragma unroll
        for (int i = 0; i < 4; ++i) {
            int c = tid + i * GM_TH;
            int col = c >> 3, k8 = c & 7;
            *(bf16x8*)&Bs[col][k8 * 8] =
                *(const bf16x8*)(Bcat + (size_t)col * KTOT + kb + k8 * 8);
        }
        __syncthreads();
        // ---- MFMA: 2 k-slices of 32 ----
        {
            const int rA   = w * 16 + (lane & 15);
            const int koff = (lane >> 4) * 8;
#pragma unroll
            for (int ks = 0; ks < 2; ++ks) {
                bf16x8 a = *(const bf16x8*)&As[rA][ks * 32 + koff];
#pragma unroll
                for (int f = 0; f < 16; ++f) {
                    bf16x8 b = *(const bf16x8*)&Bs[f * 16 + (lane & 15)][ks * 32 + koff];
                    acc[f] = __builtin_amdgcn_mfma_f32_16x16x32_bf16(a, b, acc[f], 0, 0, 0);
                }
            }
        }
        __syncthreads();
    }

    // ---- epilogue: +bias, LayerNorm per row, ReLU, store ----
    const int cl = lane & 15;
    const int g4 = lane >> 4;
    float s1[4] = {0,0,0,0}, s2[4] = {0,0,0,0};
#pragma unroll
    for (int f = 0; f < 16; ++f) {
        float bv = bl[f * 16 + cl];
#pragma unroll
        for (int j = 0; j < 4; ++j) {
            float val = acc[f][j] + bv;
            acc[f][j] = val;
            s1[j] += val;
            s2[j] += val * val;
        }
    }
#pragma unroll
    for (int m = 1; m < 16; m <<= 1) {
#pragma unroll
        for (int j = 0; j < 4; ++j) {
            s1[j] += __shfl_xor(s1[j], m);
            s2[j] += __shfl_xor(s2[j], m);
        }
    }
    float mu[4], rs[4];
#pragma unroll
    for (int j = 0; j < 4; ++j) {
        mu[j] = s1[j] * (1.0f / CCH);
        float var = s2[j] * (1.0f / CCH) - mu[j] * mu[j];
        rs[j] = rsqrtf(var + 1e-5f);
    }
    const long rbase = brow + w * 16 + g4 * 4;
#pragma unroll
    for (int f = 0; f < 16; ++f) {
        float gm = gamma[f * 16 + cl];
        float bt = beta[f * 16 + cl];
#pragma unroll
        for (int j = 0; j < 4; ++j) {
            long r = rbase + j;
            if (r < Nrows) {
                float v = (acc[f][j] - mu[j]) * rs[j] * gm + bt;
                v = fmaxf(v, 0.f);
                if (outf) outf[r * CCH + f * 16 + cl] = v;
                if (outb) outb[r * CCH + f * 16 + cl] = f2bf(v);
            }
        }
    }
}

extern "C" void kernel_launch(void* const* d_in, const int* in_sizes, int n_in,
                              void* d_out, int out_size, void* d_ws, size_t ws_size,
                              hipStream_t stream) {
    const float* x_user = (const float*)d_in[0];
    const float* x_item = (const float*)d_in[1];
    const int*   ei_u2i = (const int*)d_in[2];
    const int*   ei_i2u = (const int*)d_in[3];
    const float* Wl_u2i = (const float*)d_in[4];
    const float* bl_u2i = (const float*)d_in[5];
    const float* Wr_u2i = (const float*)d_in[6];
    const float* Wl_i2u = (const float*)d_in[7];
    const float* bl_i2u = (const float*)d_in[8];
    const float* Wr_i2u = (const float*)d_in[9];
    const float* g_user = (const float*)d_in[10];
    const float* b_user = (const float*)d_in[11];
    const float* g_item = (const float*)d_in[12];
    const float* b_item = (const float*)d_in[13];

    const int N = in_sizes[0] / CCH;
    const int E = in_sizes[2] / 2;
    const size_t NC = (size_t)N * CCH;
    const int nb = (N + SCB - 1) / SCB;

    // workspace layout (~210 MB)
    char* p = (char*)d_ws;
    unsigned short* xb_u   = (unsigned short*)p; p += NC * sizeof(unsigned short);
    unsigned short* xb_i   = (unsigned short*)p; p += NC * sizeof(unsigned short);
    unsigned short* mean_i = (unsigned short*)p; p += NC * sizeof(unsigned short);
    unsigned short* mean_u = (unsigned short*)p; p += NC * sizeof(unsigned short);
    unsigned short* wc_u2i = (unsigned short*)p; p += (size_t)2 * CCH * KTOT * sizeof(unsigned short);
    unsigned short* wc_i2u = (unsigned short*)p; p += (size_t)2 * CCH * KTOT * sizeof(unsigned short);
    int* cnt_i  = (int*)p; p += (size_t)N * sizeof(int);   // doubles as fill cursor
    int* cnt_u  = (int*)p; p += (size_t)N * sizeof(int);
    int* rs_i   = (int*)p; p += (size_t)(N + 1) * sizeof(int);
    int* rs_u   = (int*)p; p += (size_t)(N + 1) * sizeof(int);
    int* el_i   = (int*)p; p += (size_t)E * sizeof(int);
    int* el_u   = (int*)p; p += (size_t)E * sizeof(int);
    int* bs_i   = (int*)p; p += 256 * sizeof(int);
    int* bs_u   = (int*)p; p += 256 * sizeof(int);

    float* out_user = (float*)d_out;
    float* out_item = out_user + NC;

    const int eb = (E + 255) / 256;
    const int cb = (int)((NC / 8 + 255) / 256);
    const int gm_blocks = (N + GM_BM - 1) / GM_BM;
    const int gw_blocks = (int)(((size_t)N * 32 + 255) / 256);   // half-wave per node

    // ---- CSR build ----
    hipMemsetAsync(cnt_i, 0, (size_t)N * sizeof(int), stream);
    hipMemsetAsync(cnt_u, 0, (size_t)N * sizeof(int), stream);
    hist_kernel<<<eb, 256, 0, stream>>>(ei_u2i, E, cnt_i);
    hist_kernel<<<eb, 256, 0, stream>>>(ei_i2u, E, cnt_u);
    scan_part<<<nb, 256, 0, stream>>>(cnt_i, N, bs_i);
    scan_part<<<nb, 256, 0, stream>>>(cnt_u, N, bs_u);
    scan_bsum<<<2, 256, 0, stream>>>(bs_i, bs_u, nb);
    scan_apply<<<nb, 256, 0, stream>>>(cnt_i, bs_i, N, E, rs_i, cnt_i);
    scan_apply<<<nb, 256, 0, stream>>>(cnt_u, bs_u, N, E, rs_u, cnt_u);
    fill_kernel<<<eb, 256, 0, stream>>>(ei_u2i, E, rs_i, cnt_i, el_i);
    fill_kernel<<<eb, 256, 0, stream>>>(ei_i2u, E, rs_u, cnt_u, el_u);

    // ---- weight concat + bf16 (once) ----
    cvt_wcat<<<dim3(32, 2), 256, 0, stream>>>(Wl_u2i, Wr_u2i, wc_u2i);
    cvt_wcat<<<dim3(32, 2), 256, 0, stream>>>(Wl_i2u, Wr_i2u, wc_i2u);

    // ---- bf16 copies of inputs ----
    cvt_bf16<<<cb, 256, 0, stream>>>(x_user, xb_u, (long)NC);
    cvt_bf16<<<cb, 256, 0, stream>>>(x_item, xb_i, (long)NC);

    // ---- layer 1 (bf16 activations in-place over xb_*) ----
    gather_mean<<<gw_blocks, 256, 0, stream>>>(xb_u, rs_i, el_i, mean_i, N);
    gather_mean<<<gw_blocks, 256, 0, stream>>>(xb_i, rs_u, el_u, mean_u, N);
    sage_gemm_ln<<<gm_blocks, GM_TH, 0, stream>>>(mean_i, xb_i, wc_u2i,
        bl_u2i, g_item, b_item, nullptr, xb_i, N);
    sage_gemm_ln<<<gm_blocks, GM_TH, 0, stream>>>(mean_u, xb_u, wc_i2u,
        bl_i2u, g_user, b_user, nullptr, xb_u, N);

    // ---- layer 2 (fp32 out to d_out) ----
    gather_mean<<<gw_blocks, 256, 0, stream>>>(xb_u, rs_i, el_i, mean_i, N);
    gather_mean<<<gw_blocks, 256, 0, stream>>>(xb_i, rs_u, el_u, mean_u, N);
    sage_gemm_ln<<<gm_blocks, GM_TH, 0, stream>>>(mean_i, xb_i, wc_u2i + (size_t)CCH * KTOT,
        bl_u2i + CCH, g_item + CCH, b_item + CCH, out_item, nullptr, N);
    sage_gemm_ln<<<gm_blocks, GM_TH, 0, stream>>>(mean_u, xb_u, wc_i2u + (size_t)CCH * KTOT,
        bl_i2u + CCH, g_user + CCH, b_user + CCH, out_user, nullptr, N);
}

// Round 6
// 688.935 us; speedup vs baseline: 1.2539x; 1.2539x over previous
//
#include <hip/hip_runtime.h>

#define CCH 256      // channels
#define KTOT 512     // mean(256) ++ x_dst(256)
#define GM_BM 128    // rows per block in GEMM
#define GM_BK 64     // K-step
#define GM_TH 512    // threads (8 waves: 2 row-groups x 4 col-groups)
#define LDST 72      // padded LDS stride (bf16 elems)
#define SCB 2048     // scan elems per block (256 thr x 8)

using f32x4  = __attribute__((ext_vector_type(4))) float;
using bf16x8 = __attribute__((ext_vector_type(8))) short;
using s16x4  = __attribute__((ext_vector_type(4))) short;

__device__ __forceinline__ unsigned short f2bf(float f) {
    union { float f; unsigned u; } v; v.f = f;
    unsigned r = v.u + 0x7FFFu + ((v.u >> 16) & 1u);   // RNE
    return (unsigned short)(r >> 16);
}
__device__ __forceinline__ float bf2f(short h) {
    union { unsigned u; float f; } v;
    v.u = ((unsigned)(unsigned short)h) << 16;
    return v.f;
}

// ---------------- fp32 -> bf16 convert ----------------
__global__ __launch_bounds__(256)
void cvt_bf16(const float* __restrict__ x, unsigned short* __restrict__ y, long n) {
    long i = ((long)blockIdx.x * 256 + threadIdx.x) * 8;
    if (i >= n) return;
    float4 a = *(const float4*)(x + i);
    float4 b = *(const float4*)(x + i + 4);
    bf16x8 pk;
    pk[0]=(short)f2bf(a.x); pk[1]=(short)f2bf(a.y); pk[2]=(short)f2bf(a.z); pk[3]=(short)f2bf(a.w);
    pk[4]=(short)f2bf(b.x); pk[5]=(short)f2bf(b.y); pk[6]=(short)f2bf(b.z); pk[7]=(short)f2bf(b.w);
    *(bf16x8*)(y + i) = pk;
}

// ------- W concat + bf16: out[l][col][k] = (k<256 ? Wl[l][col][k] : Wr[l][col][k-256]) -------
__global__ __launch_bounds__(256)
void cvt_wcat(const float* __restrict__ Wl, const float* __restrict__ Wr,
              unsigned short* __restrict__ out) {
    const int l = blockIdx.y;
    const float* wl = Wl + (size_t)l * CCH * CCH;
    const float* wr = Wr + (size_t)l * CCH * CCH;
    unsigned short* o = out + (size_t)l * CCH * KTOT;
    int idx = (blockIdx.x * 256 + threadIdx.x) * 8;     // 0..65528
    int col = idx >> 8, k = idx & 255;
    {
        float4 a = *(const float4*)(wl + col * CCH + k);
        float4 b = *(const float4*)(wl + col * CCH + k + 4);
        bf16x8 pk;
        pk[0]=(short)f2bf(a.x); pk[1]=(short)f2bf(a.y); pk[2]=(short)f2bf(a.z); pk[3]=(short)f2bf(a.w);
        pk[4]=(short)f2bf(b.x); pk[5]=(short)f2bf(b.y); pk[6]=(short)f2bf(b.z); pk[7]=(short)f2bf(b.w);
        *(bf16x8*)(o + (size_t)col * KTOT + k) = pk;
    }
    {
        float4 a = *(const float4*)(wr + col * CCH + k);
        float4 b = *(const float4*)(wr + col * CCH + k + 4);
        bf16x8 pk;
        pk[0]=(short)f2bf(a.x); pk[1]=(short)f2bf(a.y); pk[2]=(short)f2bf(a.z); pk[3]=(short)f2bf(a.w);
        pk[4]=(short)f2bf(b.x); pk[5]=(short)f2bf(b.y); pk[6]=(short)f2bf(b.z); pk[7]=(short)f2bf(b.w);
        *(bf16x8*)(o + (size_t)col * KTOT + CCH + k) = pk;
    }
}

// ---------------- CSR build ----------------
__global__ __launch_bounds__(256)
void hist_kernel(const int* __restrict__ ei, int E, int* __restrict__ cnt) {
    int e = blockIdx.x * blockDim.x + threadIdx.x;
    if (e < E) atomicAdd(&cnt[ei[E + e]], 1);
}

__global__ __launch_bounds__(256)
void scan_part(const int* __restrict__ cnt, int N, int* __restrict__ bsum) {
    __shared__ int sw[4];
    int t = threadIdx.x;
    int base = blockIdx.x * SCB + t * 8;
    int s = 0;
#pragma unroll
    for (int j = 0; j < 8; ++j) { int idx = base + j; s += (idx < N) ? cnt[idx] : 0; }
    for (int m = 1; m < 64; m <<= 1) s += __shfl_xor(s, m);
    if ((t & 63) == 0) sw[t >> 6] = s;
    __syncthreads();
    if (t == 0) bsum[blockIdx.x] = sw[0] + sw[1] + sw[2] + sw[3];
}

__global__ __launch_bounds__(256)
void scan_bsum(int* __restrict__ ba, int* __restrict__ bb, int nb) {
    int* b = blockIdx.x ? bb : ba;
    __shared__ int s[256];
    int t = threadIdx.x;
    int v = (t < nb) ? b[t] : 0;
    s[t] = v;
    __syncthreads();
    for (int o = 1; o < 256; o <<= 1) {
        int u = 0;
        if (t >= o) u = s[t - o];
        __syncthreads();
        if (t >= o) s[t] += u;
        __syncthreads();
    }
    if (t < nb) b[t] = s[t] - v;   // exclusive
}

__global__ __launch_bounds__(256)
void scan_apply(const int* __restrict__ cnt, const int* __restrict__ bsum,
                int N, int E, int* __restrict__ rowstart, int* __restrict__ cursor) {
    __shared__ int sw[4];
    int t = threadIdx.x;
    int base = blockIdx.x * SCB + t * 8;
    int v[8]; int s = 0;
#pragma unroll
    for (int j = 0; j < 8; ++j) { int idx = base + j; v[j] = (idx < N) ? cnt[idx] : 0; s += v[j]; }
    int own = s;
    for (int m = 1; m < 64; m <<= 1) {
        int u = __shfl_up(s, m);
        if ((t & 63) >= m) s += u;
    }
    if ((t & 63) == 63) sw[t >> 6] = s;
    __syncthreads();
    int w = t >> 6, woff = 0;
    if (w > 0) woff += sw[0];
    if (w > 1) woff += sw[1];
    if (w > 2) woff += sw[2];
    int excl = bsum[blockIdx.x] + woff + s - own;
#pragma unroll
    for (int j = 0; j < 8; ++j) {
        int idx = base + j;
        if (idx < N) { rowstart[idx] = excl; excl += v[j]; cursor[idx] = 0; }
    }
    if (blockIdx.x == 0 && t == 0) rowstart[N] = E;
}

__global__ __launch_bounds__(256)
void fill_kernel(const int* __restrict__ ei, int E, const int* __restrict__ rowstart,
                 int* __restrict__ cursor, int* __restrict__ elist) {
    int e = blockIdx.x * blockDim.x + threadIdx.x;
    if (e < E) {
        int dst = ei[E + e];
        int p = atomicAdd(&cursor[dst], 1);
        elist[rowstart[dst] + p] = ei[e];
    }
}

// ------------- gather + mean (bf16): one HALF-wave (32 lanes x 16B) per node -------------
__global__ __launch_bounds__(256)
void gather_mean(const unsigned short* __restrict__ xsrc, const int* __restrict__ rowstart,
                 const int* __restrict__ elist, unsigned short* __restrict__ mean, int N) {
    int node = (blockIdx.x * blockDim.x + threadIdx.x) >> 5;
    int ln   = threadIdx.x & 31;
    if (node >= N) return;
    int lo = rowstart[node], hi = rowstart[node + 1];
    float a[8] = {0.f,0.f,0.f,0.f,0.f,0.f,0.f,0.f};
    for (int i = lo; i < hi; ++i) {
        int s = elist[i];
        bf16x8 v = *((const bf16x8*)(xsrc + (size_t)s * CCH) + ln);
#pragma unroll
        for (int j = 0; j < 8; ++j) a[j] += bf2f(v[j]);
    }
    float r = (hi > lo) ? 1.0f / (float)(hi - lo) : 0.0f;
    bf16x8 pk;
#pragma unroll
    for (int j = 0; j < 8; ++j) pk[j] = (short)f2bf(a[j] * r);
    *((bf16x8*)(mean + (size_t)node * CCH) + ln) = pk;
}

// ------- fused: h = LNReLU( [mean|xdst] @ Bcat^T + bl ); write fp32 or bf16 -------
// 8 waves: wave w -> (wr = w>>2, wc = w&3); wave tile 64 rows x 64 cols = 4x4 frags
__global__ __launch_bounds__(GM_TH, 2)
void sage_gemm_ln(const unsigned short* __restrict__ mean,
                  const unsigned short* __restrict__ xdst,
                  const unsigned short* __restrict__ Bcat,   // [256][512] bf16
                  const float* __restrict__ bl,
                  const float* __restrict__ gamma, const float* __restrict__ beta,
                  float* __restrict__ outf, unsigned short* __restrict__ outb, int Nrows)
{
    __shared__ __align__(16) unsigned short As[GM_BM][LDST];
    __shared__ __align__(16) unsigned short Bs[CCH][LDST];

    const int tid  = threadIdx.x;
    const int lane = tid & 63;
    const int wr   = tid >> 8;                 // 0..1 (waves 0-3 -> 0, 4-7 -> 1)
    const int wc   = (tid >> 6) & 3;           // 0..3
    const long brow = (long)blockIdx.x * GM_BM;

    f32x4 acc[4][4];
#pragma unroll
    for (int m = 0; m < 4; ++m)
#pragma unroll
        for (int n = 0; n < 4; ++n) acc[m][n] = (f32x4){0.f, 0.f, 0.f, 0.f};

    const int cl   = lane & 15;
    const int g    = lane >> 4;      // 0..3
    const int koff = g * 8;

    for (int kb = 0; kb < KTOT; kb += GM_BK) {
        const unsigned short* asrc = (kb < CCH) ? mean : xdst;
        const int akk = kb & (CCH - 1);
        // ---- stage A: 128 rows x 64 k ----
#pragma unroll
        for (int i = 0; i < 2; ++i) {
            int c = tid + i * GM_TH;
            int row = c >> 3, k8 = c & 7;
            long grow = brow + row;
            bf16x8 pk;
            if (grow < Nrows) {
                pk = *(const bf16x8*)(asrc + grow * CCH + akk + k8 * 8);
            } else {
#pragma unroll
                for (int j = 0; j < 8; ++j) pk[j] = 0;
            }
            *(bf16x8*)&As[row][k8 * 8] = pk;
        }
        // ---- stage B: 256 cols x 64 k from Bcat ----
#pragma unroll
        for (int i = 0; i < 4; ++i) {
            int c = tid + i * GM_TH;
            int col = c >> 3, k8 = c & 7;
            *(bf16x8*)&Bs[col][k8 * 8] =
                *(const bf16x8*)(Bcat + (size_t)col * KTOT + kb + k8 * 8);
        }
        __syncthreads();
        // ---- MFMA: 2 k-slices; 4 A-frags + 4 B-frags -> 16 MFMA each ----
#pragma unroll
        for (int ks = 0; ks < 2; ++ks) {
            bf16x8 a[4], b[4];
#pragma unroll
            for (int m = 0; m < 4; ++m)
                a[m] = *(const bf16x8*)&As[wr * 64 + m * 16 + cl][ks * 32 + koff];
#pragma unroll
            for (int n = 0; n < 4; ++n)
                b[n] = *(const bf16x8*)&Bs[wc * 64 + n * 16 + cl][ks * 32 + koff];
#pragma unroll
            for (int m = 0; m < 4; ++m)
#pragma unroll
                for (int n = 0; n < 4; ++n)
                    acc[m][n] = __builtin_amdgcn_mfma_f32_16x16x32_bf16(a[m], b[n], acc[m][n], 0, 0, 0);
        }
        __syncthreads();
    }

    // ---- epilogue: +bias, cross-wave LayerNorm, ReLU, store ----
    // partial row sums over this wave's 64 cols
    float p1[4][4], p2[4][4];   // [m][j]
#pragma unroll
    for (int m = 0; m < 4; ++m)
#pragma unroll
        for (int j = 0; j < 4; ++j) { p1[m][j] = 0.f; p2[m][j] = 0.f; }
#pragma unroll
    for (int n = 0; n < 4; ++n) {
        float bv = bl[wc * 64 + n * 16 + cl];
#pragma unroll
        for (int m = 0; m < 4; ++m)
#pragma unroll
            for (int j = 0; j < 4; ++j) {
                float v = acc[m][n][j] + bv;
                acc[m][n][j] = v;
                p1[m][j] += v;
                p2[m][j] += v * v;
            }
    }
#pragma unroll
    for (int msk = 1; msk < 16; msk <<= 1) {
#pragma unroll
        for (int m = 0; m < 4; ++m)
#pragma unroll
            for (int j = 0; j < 4; ++j) {
                p1[m][j] += __shfl_xor(p1[m][j], msk);
                p2[m][j] += __shfl_xor(p2[m][j], msk);
            }
    }
    // cross-wave reduction table: red[row128][wc] (float2), overlaid on As
    float2* red = (float2*)&As[0][0];
    if (cl == 0) {
#pragma unroll
        for (int m = 0; m < 4; ++m)
#pragma unroll
            for (int j = 0; j < 4; ++j) {
                int rl = wr * 64 + m * 16 + g * 4 + j;
                red[rl * 4 + wc] = make_float2(p1[m][j], p2[m][j]);
            }
    }
    __syncthreads();

    float gm[4], bt[4];
#pragma unroll
    for (int n = 0; n < 4; ++n) {
        gm[n] = gamma[wc * 64 + n * 16 + cl];
        bt[n] = beta[wc * 64 + n * 16 + cl];
    }
#pragma unroll
    for (int m = 0; m < 4; ++m) {
#pragma unroll
        for (int j = 0; j < 4; ++j) {
            int rl = wr * 64 + m * 16 + g * 4 + j;
            f32x4 u0 = *(const f32x4*)&red[rl * 4 + 0];
            f32x4 u1 = *(const f32x4*)&red[rl * 4 + 2];
            float s1 = u0[0] + u0[2] + u1[0] + u1[2];
            float s2 = u0[1] + u0[3] + u1[1] + u1[3];
            float mu = s1 * (1.0f / CCH);
            float var = s2 * (1.0f / CCH) - mu * mu;
            float rsd = rsqrtf(var + 1e-5f);
            long r = brow + rl;
            if (r < Nrows) {
#pragma unroll
                for (int n = 0; n < 4; ++n) {
                    float v = (acc[m][n][j] - mu) * rsd * gm[n] + bt[n];
                    v = fmaxf(v, 0.f);
                    long off = r * CCH + wc * 64 + n * 16 + cl;
                    if (outf) outf[off] = v;
                    if (outb) outb[off] = f2bf(v);
                }
            }
        }
    }
}

extern "C" void kernel_launch(void* const* d_in, const int* in_sizes, int n_in,
                              void* d_out, int out_size, void* d_ws, size_t ws_size,
                              hipStream_t stream) {
    const float* x_user = (const float*)d_in[0];
    const float* x_item = (const float*)d_in[1];
    const int*   ei_u2i = (const int*)d_in[2];
    const int*   ei_i2u = (const int*)d_in[3];
    const float* Wl_u2i = (const float*)d_in[4];
    const float* bl_u2i = (const float*)d_in[5];
    const float* Wr_u2i = (const float*)d_in[6];
    const float* Wl_i2u = (const float*)d_in[7];
    const float* bl_i2u = (const float*)d_in[8];
    const float* Wr_i2u = (const float*)d_in[9];
    const float* g_user = (const float*)d_in[10];
    const float* b_user = (const float*)d_in[11];
    const float* g_item = (const float*)d_in[12];
    const float* b_item = (const float*)d_in[13];

    const int N = in_sizes[0] / CCH;
    const int E = in_sizes[2] / 2;
    const size_t NC = (size_t)N * CCH;
    const int nb = (N + SCB - 1) / SCB;

    // workspace layout (~210 MB)
    char* p = (char*)d_ws;
    unsigned short* xb_u   = (unsigned short*)p; p += NC * sizeof(unsigned short);
    unsigned short* xb_i   = (unsigned short*)p; p += NC * sizeof(unsigned short);
    unsigned short* mean_i = (unsigned short*)p; p += NC * sizeof(unsigned short);
    unsigned short* mean_u = (unsigned short*)p; p += NC * sizeof(unsigned short);
    unsigned short* wc_u2i = (unsigned short*)p; p += (size_t)2 * CCH * KTOT * sizeof(unsigned short);
    unsigned short* wc_i2u = (unsigned short*)p; p += (size_t)2 * CCH * KTOT * sizeof(unsigned short);
    int* cnt_i  = (int*)p; p += (size_t)N * sizeof(int);   // doubles as fill cursor
    int* cnt_u  = (int*)p; p += (size_t)N * sizeof(int);
    int* rs_i   = (int*)p; p += (size_t)(N + 1) * sizeof(int);
    int* rs_u   = (int*)p; p += (size_t)(N + 1) * sizeof(int);
    int* el_i   = (int*)p; p += (size_t)E * sizeof(int);
    int* el_u   = (int*)p; p += (size_t)E * sizeof(int);
    int* bs_i   = (int*)p; p += 256 * sizeof(int);
    int* bs_u   = (int*)p; p += 256 * sizeof(int);

    float* out_user = (float*)d_out;
    float* out_item = out_user + NC;

    const int eb = (E + 255) / 256;
    const int cb = (int)((NC / 8 + 255) / 256);
    const int gm_blocks = (N + GM_BM - 1) / GM_BM;
    const int gw_blocks = (int)(((size_t)N * 32 + 255) / 256);   // half-wave per node

    // ---- CSR build ----
    hipMemsetAsync(cnt_i, 0, (size_t)N * sizeof(int), stream);
    hipMemsetAsync(cnt_u, 0, (size_t)N * sizeof(int), stream);
    hist_kernel<<<eb, 256, 0, stream>>>(ei_u2i, E, cnt_i);
    hist_kernel<<<eb, 256, 0, stream>>>(ei_i2u, E, cnt_u);
    scan_part<<<nb, 256, 0, stream>>>(cnt_i, N, bs_i);
    scan_part<<<nb, 256, 0, stream>>>(cnt_u, N, bs_u);
    scan_bsum<<<2, 256, 0, stream>>>(bs_i, bs_u, nb);
    scan_apply<<<nb, 256, 0, stream>>>(cnt_i, bs_i, N, E, rs_i, cnt_i);
    scan_apply<<<nb, 256, 0, stream>>>(cnt_u, bs_u, N, E, rs_u, cnt_u);
    fill_kernel<<<eb, 256, 0, stream>>>(ei_u2i, E, rs_i, cnt_i, el_i);
    fill_kernel<<<eb, 256, 0, stream>>>(ei_i2u, E, rs_u, cnt_u, el_u);

    // ---- weight concat + bf16 (once) ----
    cvt_wcat<<<dim3(32, 2), 256, 0, stream>>>(Wl_u2i, Wr_u2i, wc_u2i);
    cvt_wcat<<<dim3(32, 2), 256, 0, stream>>>(Wl_i2u, Wr_i2u, wc_i2u);

    // ---- bf16 copies of inputs ----
    cvt_bf16<<<cb, 256, 0, stream>>>(x_user, xb_u, (long)NC);
    cvt_bf16<<<cb, 256, 0, stream>>>(x_item, xb_i, (long)NC);

    // ---- layer 1 (bf16 activations in-place over xb_*) ----
    gather_mean<<<gw_blocks, 256, 0, stream>>>(xb_u, rs_i, el_i, mean_i, N);
    gather_mean<<<gw_blocks, 256, 0, stream>>>(xb_i, rs_u, el_u, mean_u, N);
    sage_gemm_ln<<<gm_blocks, GM_TH, 0, stream>>>(mean_i, xb_i, wc_u2i,
        bl_u2i, g_item, b_item, nullptr, xb_i, N);
    sage_gemm_ln<<<gm_blocks, GM_TH, 0, stream>>>(mean_u, xb_u, wc_i2u,
        bl_i2u, g_user, b_user, nullptr, xb_u, N);

    // ---- layer 2 (fp32 out to d_out) ----
    gather_mean<<<gw_blocks, 256, 0, stream>>>(xb_u, rs_i, el_i, mean_i, N);
    gather_mean<<<gw_blocks, 256, 0, stream>>>(xb_i, rs_u, el_u, mean_u, N);
    sage_gemm_ln<<<gm_blocks, GM_TH, 0, stream>>>(mean_i, xb_i, wc_u2i + (size_t)CCH * KTOT,
        bl_u2i + CCH, g_item + CCH, b_item + CCH, out_item, nullptr, N);
    sage_gemm_ln<<<gm_blocks, GM_TH, 0, stream>>>(mean_u, xb_u, wc_i2u + (size_t)CCH * KTOT,
        bl_i2u + CCH, g_user + CCH, b_user + CCH, out_user, nullptr, N);
}

// Round 8
// 570.742 us; speedup vs baseline: 1.5135x; 1.2071x over previous
//
#include <hip/hip_runtime.h>

#define CCH 256      // channels
#define KTOT 512     // mean(256) ++ x_dst(256)
#define GM_BM 128    // rows per block in GEMM
#define GM_BK 64     // K-step (elems; 128 B per row-chunk = 8 slots of 16 B)
#define GM_TH 512    // threads (8 waves: 2 row-groups x 4 col-groups)
#define SCB 2048     // scan elems per block (256 thr x 8)

using f32x4  = __attribute__((ext_vector_type(4))) float;
using bf16x8 = __attribute__((ext_vector_type(8))) short;
using s16x4  = __attribute__((ext_vector_type(4))) short;

__device__ __forceinline__ unsigned short f2bf(float f) {
    union { float f; unsigned u; } v; v.f = f;
    unsigned r = v.u + 0x7FFFu + ((v.u >> 16) & 1u);   // RNE
    return (unsigned short)(r >> 16);
}
__device__ __forceinline__ float bf2f(short h) {
    union { unsigned u; float f; } v;
    v.u = ((unsigned)(unsigned short)h) << 16;
    return v.f;
}
__device__ __forceinline__ void gload16(const void* g, void* l) {
    __builtin_amdgcn_global_load_lds(
        (const __attribute__((address_space(1))) unsigned int*)g,
        (__attribute__((address_space(3))) unsigned int*)l, 16, 0, 0);
}

// ---------------- fp32 -> bf16 convert ----------------
__global__ __launch_bounds__(256)
void cvt_bf16(const float* __restrict__ x, unsigned short* __restrict__ y, long n) {
    long i = ((long)blockIdx.x * 256 + threadIdx.x) * 8;
    if (i >= n) return;
    float4 a = *(const float4*)(x + i);
    float4 b = *(const float4*)(x + i + 4);
    bf16x8 pk;
    pk[0]=(short)f2bf(a.x); pk[1]=(short)f2bf(a.y); pk[2]=(short)f2bf(a.z); pk[3]=(short)f2bf(a.w);
    pk[4]=(short)f2bf(b.x); pk[5]=(short)f2bf(b.y); pk[6]=(short)f2bf(b.z); pk[7]=(short)f2bf(b.w);
    *(bf16x8*)(y + i) = pk;
}

// ------- W concat + bf16: out[l][col][k] = (k<256 ? Wl[l][col][k] : Wr[l][col][k-256]) -------
__global__ __launch_bounds__(256)
void cvt_wcat(const float* __restrict__ Wl, const float* __restrict__ Wr,
              unsigned short* __restrict__ out) {
    const int l = blockIdx.y;
    const float* wl = Wl + (size_t)l * CCH * CCH;
    const float* wr = Wr + (size_t)l * CCH * CCH;
    unsigned short* o = out + (size_t)l * CCH * KTOT;
    int idx = (blockIdx.x * 256 + threadIdx.x) * 8;     // 0..65528
    int col = idx >> 8, k = idx & 255;
    {
        float4 a = *(const float4*)(wl + col * CCH + k);
        float4 b = *(const float4*)(wl + col * CCH + k + 4);
        bf16x8 pk;
        pk[0]=(short)f2bf(a.x); pk[1]=(short)f2bf(a.y); pk[2]=(short)f2bf(a.z); pk[3]=(short)f2bf(a.w);
        pk[4]=(short)f2bf(b.x); pk[5]=(short)f2bf(b.y); pk[6]=(short)f2bf(b.z); pk[7]=(short)f2bf(b.w);
        *(bf16x8*)(o + (size_t)col * KTOT + k) = pk;
    }
    {
        float4 a = *(const float4*)(wr + col * CCH + k);
        float4 b = *(const float4*)(wr + col * CCH + k + 4);
        bf16x8 pk;
        pk[0]=(short)f2bf(a.x); pk[1]=(short)f2bf(a.y); pk[2]=(short)f2bf(a.z); pk[3]=(short)f2bf(a.w);
        pk[4]=(short)f2bf(b.x); pk[5]=(short)f2bf(b.y); pk[6]=(short)f2bf(b.z); pk[7]=(short)f2bf(b.w);
        *(bf16x8*)(o + (size_t)col * KTOT + CCH + k) = pk;
    }
}

// ---------------- CSR build ----------------
__global__ __launch_bounds__(256)
void hist_kernel(const int* __restrict__ ei, int E, int* __restrict__ cnt) {
    int e = blockIdx.x * blockDim.x + threadIdx.x;
    if (e < E) atomicAdd(&cnt[ei[E + e]], 1);
}

__global__ __launch_bounds__(256)
void scan_part(const int* __restrict__ cnt, int N, int* __restrict__ bsum) {
    __shared__ int sw[4];
    int t = threadIdx.x;
    int base = blockIdx.x * SCB + t * 8;
    int s = 0;
#pragma unroll
    for (int j = 0; j < 8; ++j) { int idx = base + j; s += (idx < N) ? cnt[idx] : 0; }
    for (int m = 1; m < 64; m <<= 1) s += __shfl_xor(s, m);
    if ((t & 63) == 0) sw[t >> 6] = s;
    __syncthreads();
    if (t == 0) bsum[blockIdx.x] = sw[0] + sw[1] + sw[2] + sw[3];
}

__global__ __launch_bounds__(256)
void scan_bsum(int* __restrict__ ba, int* __restrict__ bb, int nb) {
    int* b = blockIdx.x ? bb : ba;
    __shared__ int s[256];
    int t = threadIdx.x;
    int v = (t < nb) ? b[t] : 0;
    s[t] = v;
    __syncthreads();
    for (int o = 1; o < 256; o <<= 1) {
        int u = 0;
        if (t >= o) u = s[t - o];
        __syncthreads();
        if (t >= o) s[t] += u;
        __syncthreads();
    }
    if (t < nb) b[t] = s[t] - v;   // exclusive
}

__global__ __launch_bounds__(256)
void scan_apply(const int* __restrict__ cnt, const int* __restrict__ bsum,
                int N, int E, int* __restrict__ rowstart, int* __restrict__ cursor) {
    __shared__ int sw[4];
    int t = threadIdx.x;
    int base = blockIdx.x * SCB + t * 8;
    int v[8]; int s = 0;
#pragma unroll
    for (int j = 0; j < 8; ++j) { int idx = base + j; v[j] = (idx < N) ? cnt[idx] : 0; s += v[j]; }
    int own = s;
    for (int m = 1; m < 64; m <<= 1) {
        int u = __shfl_up(s, m);
        if ((t & 63) >= m) s += u;
    }
    if ((t & 63) == 63) sw[t >> 6] = s;
    __syncthreads();
    int w = t >> 6, woff = 0;
    if (w > 0) woff += sw[0];
    if (w > 1) woff += sw[1];
    if (w > 2) woff += sw[2];
    int excl = bsum[blockIdx.x] + woff + s - own;
#pragma unroll
    for (int j = 0; j < 8; ++j) {
        int idx = base + j;
        if (idx < N) { rowstart[idx] = excl; excl += v[j]; cursor[idx] = 0; }
    }
    if (blockIdx.x == 0 && t == 0) rowstart[N] = E;
}

__global__ __launch_bounds__(256)
void fill_kernel(const int* __restrict__ ei, int E, const int* __restrict__ rowstart,
                 int* __restrict__ cursor, int* __restrict__ elist) {
    int e = blockIdx.x * blockDim.x + threadIdx.x;
    if (e < E) {
        int dst = ei[E + e];
        int p = atomicAdd(&cursor[dst], 1);
        elist[rowstart[dst] + p] = ei[e];
    }
}

// ------------- gather + mean (bf16), both directions in one dispatch -------------
__global__ __launch_bounds__(256)
void gather_mean(const unsigned short* __restrict__ xs0, const int* __restrict__ rs0,
                 const int* __restrict__ el0, unsigned short* __restrict__ mn0,
                 const unsigned short* __restrict__ xs1, const int* __restrict__ rs1,
                 const int* __restrict__ el1, unsigned short* __restrict__ mn1, int N) {
    const unsigned short* xsrc = blockIdx.y ? xs1 : xs0;
    const int* rowstart        = blockIdx.y ? rs1 : rs0;
    const int* elist           = blockIdx.y ? el1 : el0;
    unsigned short* mean       = blockIdx.y ? mn1 : mn0;
    int node = (blockIdx.x * blockDim.x + threadIdx.x) >> 5;
    int ln   = threadIdx.x & 31;
    if (node >= N) return;
    int lo = rowstart[node], hi = rowstart[node + 1];
    float a[8] = {0.f,0.f,0.f,0.f,0.f,0.f,0.f,0.f};
    for (int i = lo; i < hi; ++i) {
        int s = elist[i];
        bf16x8 v = *((const bf16x8*)(xsrc + (size_t)s * CCH) + ln);
#pragma unroll
        for (int j = 0; j < 8; ++j) a[j] += bf2f(v[j]);
    }
    float r = (hi > lo) ? 1.0f / (float)(hi - lo) : 0.0f;
    bf16x8 pk;
#pragma unroll
    for (int j = 0; j < 8; ++j) pk[j] = (short)f2bf(a[j] * r);
    *((bf16x8*)(mean + (size_t)node * CCH) + ln) = pk;
}

// ------- fused: h = LNReLU( [mean|xdst] @ Bcat^T + bl ); both directions via blockIdx.y -------
// 8 waves (2 row x 4 col); global_load_lds staging; XOR slot swizzle both sides.
__global__ __launch_bounds__(GM_TH, 4)
void sage_gemm_ln(const unsigned short* __restrict__ mean0,
                  const unsigned short* __restrict__ xdst0,
                  const unsigned short* __restrict__ Bc0,
                  const float* __restrict__ bl0,
                  const float* __restrict__ gm0, const float* __restrict__ bt0,
                  float* __restrict__ outf0, unsigned short* __restrict__ outb0,
                  const unsigned short* __restrict__ mean1,
                  const unsigned short* __restrict__ xdst1,
                  const unsigned short* __restrict__ Bc1,
                  const float* __restrict__ bl1,
                  const float* __restrict__ gm1, const float* __restrict__ bt1,
                  float* __restrict__ outf1, unsigned short* __restrict__ outb1,
                  int Nrows)
{
    const int dir = blockIdx.y;
    const unsigned short* mean = dir ? mean1 : mean0;
    const unsigned short* xdst = dir ? xdst1 : xdst0;
    const unsigned short* Bcat = dir ? Bc1   : Bc0;
    const float* bl    = dir ? bl1 : bl0;
    const float* gamma = dir ? gm1 : gm0;
    const float* beta  = dir ? bt1 : bt0;
    float* outf          = dir ? outf1 : outf0;
    unsigned short* outb = dir ? outb1 : outb0;

    __shared__ __align__(16) unsigned short As[GM_BM * GM_BK];   // 16 KB, swizzled slots
    __shared__ __align__(16) unsigned short Bs[CCH * GM_BK];     // 32 KB

    const int tid  = threadIdx.x;
    const int lane = tid & 63;
    const int wr   = tid >> 8;                 // 0..1
    const int wc   = (tid >> 6) & 3;           // 0..3
    const int cl   = lane & 15;
    const int g    = lane >> 4;                // 0..3
    const long brow = (long)blockIdx.x * GM_BM;

    f32x4 acc[4][4];
#pragma unroll
    for (int m = 0; m < 4; ++m)
#pragma unroll
        for (int n = 0; n < 4; ++n) acc[m][n] = (f32x4){0.f, 0.f, 0.f, 0.f};

    for (int kb = 0; kb < KTOT; kb += GM_BK) {
        const unsigned short* asrc = (kb < CCH) ? mean : xdst;
        const int akk = kb & (CCH - 1);
        // ---- stage A: 128 rows x 64 k via global_load_lds; source pre-swizzled ----
#pragma unroll
        for (int i = 0; i < 2; ++i) {
            int c = tid + i * GM_TH;
            int row = c >> 3, sl = c & 7;
            long grow = brow + row;
            if (grow > (long)Nrows - 1) grow = (long)Nrows - 1;   // clamp (no OOB, no NaN)
            gload16(asrc + grow * CCH + akk + ((sl ^ (row & 7)) << 3),
                    (char*)As + c * 16);
        }
        // ---- stage B: 256 cols x 64 k ----
#pragma unroll
        for (int i = 0; i < 4; ++i) {
            int c = tid + i * GM_TH;
            int col = c >> 3, sl = c & 7;
            gload16(Bcat + (size_t)col * KTOT + kb + ((sl ^ (col & 7)) << 3),
                    (char*)Bs + c * 16);
        }
        __syncthreads();
        // ---- MFMA: 2 k-slices; swizzled ds_read_b128 (slot ^ (cl&7)) ----
#pragma unroll
        for (int ks = 0; ks < 2; ++ks) {
            const int slot = (ks * 4 + g) ^ (cl & 7);
            bf16x8 a[4];
#pragma unroll
            for (int m = 0; m < 4; ++m) {
                int row = wr * 64 + m * 16 + cl;
                a[m] = *(const bf16x8*)((const char*)As + row * 128 + slot * 16);
            }
#pragma unroll
            for (int n = 0; n < 4; ++n) {
                int col = wc * 64 + n * 16 + cl;
                bf16x8 b = *(const bf16x8*)((const char*)Bs + col * 128 + slot * 16);
#pragma unroll
                for (int m = 0; m < 4; ++m)
                    acc[m][n] = __builtin_amdgcn_mfma_f32_16x16x32_bf16(a[m], b, acc[m][n], 0, 0, 0);
            }
        }
        __syncthreads();
    }

    // ---- epilogue: +bias, cross-wave LayerNorm, ReLU, store ----
    float p1[4][4], p2[4][4];   // [m][j]
#pragma unroll
    for (int m = 0; m < 4; ++m)
#pragma unroll
        for (int j = 0; j < 4; ++j) { p1[m][j] = 0.f; p2[m][j] = 0.f; }
#pragma unroll
    for (int n = 0; n < 4; ++n) {
        float bv = bl[wc * 64 + n * 16 + cl];
#pragma unroll
        for (int m = 0; m < 4; ++m)
#pragma unroll
            for (int j = 0; j < 4; ++j) {
                float v = acc[m][n][j] + bv;
                acc[m][n][j] = v;
                p1[m][j] += v;
                p2[m][j] += v * v;
            }
    }
#pragma unroll
    for (int msk = 1; msk < 16; msk <<= 1) {
#pragma unroll
        for (int m = 0; m < 4; ++m)
#pragma unroll
            for (int j = 0; j < 4; ++j) {
                p1[m][j] += __shfl_xor(p1[m][j], msk);
                p2[m][j] += __shfl_xor(p2[m][j], msk);
            }
    }
    float2* red = (float2*)&As[0];   // red[row128][4], 4 KB overlay
    if (cl == 0) {
#pragma unroll
        for (int m = 0; m < 4; ++m)
#pragma unroll
            for (int j = 0; j < 4; ++j) {
                int rl = wr * 64 + m * 16 + g * 4 + j;
                red[rl * 4 + wc] = make_float2(p1[m][j], p2[m][j]);
            }
    }
    __syncthreads();

    float gmv[4], btv[4];
#pragma unroll
    for (int n = 0; n < 4; ++n) {
        gmv[n] = gamma[wc * 64 + n * 16 + cl];
        btv[n] = beta[wc * 64 + n * 16 + cl];
    }
#pragma unroll
    for (int m = 0; m < 4; ++m) {
#pragma unroll
        for (int j = 0; j < 4; ++j) {
            int rl = wr * 64 + m * 16 + g * 4 + j;
            f32x4 u0 = *(const f32x4*)&red[rl * 4 + 0];
            f32x4 u1 = *(const f32x4*)&red[rl * 4 + 2];
            float s1 = u0[0] + u0[2] + u1[0] + u1[2];
            float s2 = u0[1] + u0[3] + u1[1] + u1[3];
            float mu = s1 * (1.0f / CCH);
            float var = s2 * (1.0f / CCH) - mu * mu;
            float rsd = rsqrtf(var + 1e-5f);
            long r = brow + rl;
            if (r < Nrows) {
#pragma unroll
                for (int n = 0; n < 4; ++n) {
                    float v = (acc[m][n][j] - mu) * rsd * gmv[n] + btv[n];
                    v = fmaxf(v, 0.f);
                    long off = r * CCH + wc * 64 + n * 16 + cl;
                    if (outf) outf[off] = v;
                    if (outb) outb[off] = f2bf(v);
                }
            }
        }
    }
}

extern "C" void kernel_launch(void* const* d_in, const int* in_sizes, int n_in,
                              void* d_out, int out_size, void* d_ws, size_t ws_size,
                              hipStream_t stream) {
    const float* x_user = (const float*)d_in[0];
    const float* x_item = (const float*)d_in[1];
    const int*   ei_u2i = (const int*)d_in[2];
    const int*   ei_i2u = (const int*)d_in[3];
    const float* Wl_u2i = (const float*)d_in[4];
    const float* bl_u2i = (const float*)d_in[5];
    const float* Wr_u2i = (const float*)d_in[6];
    const float* Wl_i2u = (const float*)d_in[7];
    const float* bl_i2u = (const float*)d_in[8];
    const float* Wr_i2u = (const float*)d_in[9];
    const float* g_user = (const float*)d_in[10];
    const float* b_user = (const float*)d_in[11];
    const float* g_item = (const float*)d_in[12];
    const float* b_item = (const float*)d_in[13];

    const int N = in_sizes[0] / CCH;
    const int E = in_sizes[2] / 2;
    const size_t NC = (size_t)N * CCH;
    const int nb = (N + SCB - 1) / SCB;

    // workspace layout (~210 MB)
    char* p = (char*)d_ws;
    unsigned short* xb_u   = (unsigned short*)p; p += NC * sizeof(unsigned short);
    unsigned short* xb_i   = (unsigned short*)p; p += NC * sizeof(unsigned short);
    unsigned short* mean_i = (unsigned short*)p; p += NC * sizeof(unsigned short);
    unsigned short* mean_u = (unsigned short*)p; p += NC * sizeof(unsigned short);
    unsigned short* wc_u2i = (unsigned short*)p; p += (size_t)2 * CCH * KTOT * sizeof(unsigned short);
    unsigned short* wc_i2u = (unsigned short*)p; p += (size_t)2 * CCH * KTOT * sizeof(unsigned short);
    int* cnt_i  = (int*)p; p += (size_t)N * sizeof(int);   // doubles as fill cursor
    int* cnt_u  = (int*)p; p += (size_t)N * sizeof(int);
    int* rs_i   = (int*)p; p += (size_t)(N + 1) * sizeof(int);
    int* rs_u   = (int*)p; p += (size_t)(N + 1) * sizeof(int);
    int* el_i   = (int*)p; p += (size_t)E * sizeof(int);
    int* el_u   = (int*)p; p += (size_t)E * sizeof(int);
    int* bs_i   = (int*)p; p += 256 * sizeof(int);
    int* bs_u   = (int*)p; p += 256 * sizeof(int);

    float* out_user = (float*)d_out;
    float* out_item = out_user + NC;

    const int eb = (E + 255) / 256;
    const int cb = (int)((NC / 8 + 255) / 256);
    const int gm_blocks = (N + GM_BM - 1) / GM_BM;
    const int gw_blocks = (int)(((size_t)N * 32 + 255) / 256);   // half-wave per node

    // ---- CSR build ----
    hipMemsetAsync(cnt_i, 0, (size_t)N * sizeof(int), stream);
    hipMemsetAsync(cnt_u, 0, (size_t)N * sizeof(int), stream);
    hist_kernel<<<eb, 256, 0, stream>>>(ei_u2i, E, cnt_i);
    hist_kernel<<<eb, 256, 0, stream>>>(ei_i2u, E, cnt_u);
    scan_part<<<nb, 256, 0, stream>>>(cnt_i, N, bs_i);
    scan_part<<<nb, 256, 0, stream>>>(cnt_u, N, bs_u);
    scan_bsum<<<2, 256, 0, stream>>>(bs_i, bs_u, nb);
    scan_apply<<<nb, 256, 0, stream>>>(cnt_i, bs_i, N, E, rs_i, cnt_i);
    scan_apply<<<nb, 256, 0, stream>>>(cnt_u, bs_u, N, E, rs_u, cnt_u);
    fill_kernel<<<eb, 256, 0, stream>>>(ei_u2i, E, rs_i, cnt_i, el_i);
    fill_kernel<<<eb, 256, 0, stream>>>(ei_i2u, E, rs_u, cnt_u, el_u);

    // ---- weight concat + bf16 (once) ----
    cvt_wcat<<<dim3(32, 2), 256, 0, stream>>>(Wl_u2i, Wr_u2i, wc_u2i);
    cvt_wcat<<<dim3(32, 2), 256, 0, stream>>>(Wl_i2u, Wr_i2u, wc_i2u);

    // ---- bf16 copies of inputs ----
    cvt_bf16<<<cb, 256, 0, stream>>>(x_user, xb_u, (long)NC);
    cvt_bf16<<<cb, 256, 0, stream>>>(x_item, xb_i, (long)NC);

    for (int l = 0; l < 2; ++l) {
        const size_t wl = (size_t)l * CCH * KTOT;
        gather_mean<<<dim3(gw_blocks, 2), 256, 0, stream>>>(
            xb_u, rs_i, el_i, mean_i,
            xb_i, rs_u, el_u, mean_u, N);
        if (l == 0) {
            sage_gemm_ln<<<dim3(gm_blocks, 2), GM_TH, 0, stream>>>(
                mean_i, xb_i, wc_u2i + wl, bl_u2i + l * CCH, g_item + l * CCH, b_item + l * CCH,
                nullptr, xb_i,
                mean_u, xb_u, wc_i2u + wl, bl_i2u + l * CCH, g_user + l * CCH, b_user + l * CCH,
                nullptr, xb_u, N);
        } else {
            sage_gemm_ln<<<dim3(gm_blocks, 2), GM_TH, 0, stream>>>(
                mean_i, xb_i, wc_u2i + wl, bl_u2i + l * CCH, g_item + l * CCH, b_item + l * CCH,
                out_item, nullptr,
                mean_u, xb_u, wc_i2u + wl, bl_i2u + l * CCH, g_user + l * CCH, b_user + l * CCH,
                out_user, nullptr, N);
        }
    }
}